// Round 1
// baseline (611.731 us; speedup 1.0000x reference)
//
#include <hip/hip_runtime.h>
#include <hip/hip_bf16.h>
#include <stdint.h>

// Problem dims (fixed by reference)
#define M_ROWS 8192   // B*S
#define K_OUT  4096   // K (output features)
#define N_RED  4096   // N (reduction dim)
#define NGRP   32
#define GROUP  128

// GEMM tile
#define BM 128
#define BN 128
#define BK 32

typedef __attribute__((ext_vector_type(8))) __bf16 bf16x8;
typedef __attribute__((ext_vector_type(4))) float   f32x4;

// ---------- helpers ----------

__device__ __forceinline__ unsigned short f32_to_bf16_rn(float f) {
  uint32_t u = __float_as_uint(f);
  // round-to-nearest-even
  uint32_t r = (u + 0x7FFFu + ((u >> 16) & 1u)) >> 16;
  return (unsigned short)r;
}

// async global -> LDS, 16 bytes per lane. LDS dest is wave-uniform base +
// lane*16 (hardware rule, guide §5); global src is per-lane.
__device__ __forceinline__ void async_copy16(const void* gsrc, void* lds_base) {
  __builtin_amdgcn_global_load_lds(
      (const __attribute__((address_space(1))) uint32_t*)gsrc,
      (__attribute__((address_space(3))) uint32_t*)lds_base,
      16 /*literal!*/, 0, 0);
}

// ---------- kernel 1: x fp32 -> bf16 (8 elems/thread) ----------
__global__ __launch_bounds__(256) void cvt_x_kernel(
    const float* __restrict__ x, unsigned short* __restrict__ xb) {
  size_t idx = (size_t)blockIdx.x * 256 + threadIdx.x;  // 8 elems each
  const float4* xp = (const float4*)(x + idx * 8);
  float4 v0 = xp[0];
  float4 v1 = xp[1];
  union { unsigned short h[8]; uint4 v; } p;
  p.h[0] = f32_to_bf16_rn(v0.x);
  p.h[1] = f32_to_bf16_rn(v0.y);
  p.h[2] = f32_to_bf16_rn(v0.z);
  p.h[3] = f32_to_bf16_rn(v0.w);
  p.h[4] = f32_to_bf16_rn(v1.x);
  p.h[5] = f32_to_bf16_rn(v1.y);
  p.h[6] = f32_to_bf16_rn(v1.z);
  p.h[7] = f32_to_bf16_rn(v1.w);
  *(uint4*)(xb + idx * 8) = p.v;
}

// ---------- kernel 2: dequant W_q -> bf16 (8 elems/thread) ----------
__global__ __launch_bounds__(256) void dequant_w_kernel(
    const int* __restrict__ Wq, const float* __restrict__ scales,
    const float* __restrict__ zeros, const float* __restrict__ mu1,
    const float* __restrict__ mu2, unsigned short* __restrict__ Wb) {
  size_t idx = (size_t)blockIdx.x * 256 + threadIdx.x;  // 8 elems each
  int k = (int)(idx >> 9);          // 512 threads per row of 4096
  int n = (int)(idx & 511) << 3;    // element offset in row
  int g = n >> 7;                   // group (128 | 8, so uniform over the 8)
  float s  = scales[k * NGRP + g];
  float z  = zeros[k * NGRP + g];
  float sm = s * mu2[k];
  const int4* qp = (const int4*)(Wq + (size_t)k * N_RED + n);
  int4 q0 = qp[0];
  int4 q1 = qp[1];
  const float4* mp = (const float4*)(mu1 + n);
  float4 m0 = mp[0];
  float4 m1 = mp[1];
  union { unsigned short h[8]; uint4 v; } p;
  p.h[0] = f32_to_bf16_rn(((float)q0.x - z) * sm * m0.x);
  p.h[1] = f32_to_bf16_rn(((float)q0.y - z) * sm * m0.y);
  p.h[2] = f32_to_bf16_rn(((float)q0.z - z) * sm * m0.z);
  p.h[3] = f32_to_bf16_rn(((float)q0.w - z) * sm * m0.w);
  p.h[4] = f32_to_bf16_rn(((float)q1.x - z) * sm * m1.x);
  p.h[5] = f32_to_bf16_rn(((float)q1.y - z) * sm * m1.y);
  p.h[6] = f32_to_bf16_rn(((float)q1.z - z) * sm * m1.z);
  p.h[7] = f32_to_bf16_rn(((float)q1.w - z) * sm * m1.w);
  *(uint4*)(Wb + (size_t)k * N_RED + n) = p.v;
}

// ---------- kernel 3: bf16 GEMM C = A * B^T + bias ----------
// A: [M_ROWS][N_RED] bf16 (row-major, K-contiguous)
// B: [K_OUT][N_RED]  bf16 (row-major, K-contiguous)  == W_deq
// C: [M_ROWS][K_OUT] fp32
// m97 structure: 128x128 tile, BK=32, 4 waves (2x2), each wave 64x64 = 4x4
// frags of 16x16x32 MFMA; global_load_lds width 16 staging; 2 barriers/K-step.
__global__ __launch_bounds__(256, 3) void gemm_bt_kernel(
    const unsigned short* __restrict__ A, const unsigned short* __restrict__ B,
    const float* __restrict__ bias, float* __restrict__ C) {
  __shared__ __align__(16) unsigned short As[BM * BK];  // 8 KB
  __shared__ __align__(16) unsigned short Bs[BN * BK];  // 8 KB

  // XCD-bijective swizzle: nwg = 2048 = 8 * 256
  int bid = blockIdx.x;
  int wg = (bid & 7) * 256 + (bid >> 3);
  int rowTile = wg >> 5;   // 0..63
  int colTile = wg & 31;   // 0..31

  int tid  = threadIdx.x;
  int wave = tid >> 6;
  int lane = tid & 63;
  int wr = wave >> 1;      // wave row 0..1
  int wc = wave & 1;       // wave col 0..1
  int fr = lane & 15;      // fragment row/col index
  int fq = lane >> 4;      // quad 0..3 (k-offset = fq*8, C row base = fq*4)

  // staging lane coords: each wave-instruction covers 16 rows x 32 elems
  int srow  = lane >> 2;        // 0..15
  int scol8 = (lane & 3) * 8;   // 0,8,16,24

  const unsigned short* Ag = A + (size_t)(rowTile * BM) * N_RED;
  const unsigned short* Bg = B + (size_t)(colTile * BN) * N_RED;

  f32x4 acc[4][4] = {};

  for (int kt = 0; kt < N_RED / BK; ++kt) {
    int kbase = kt * BK;
    // ---- stage A and B tiles (4 global_load_lds per thread) ----
#pragma unroll
    for (int i = 0; i < 2; ++i) {
      int rbase = (i * 4 + wave) * 16;  // wave-uniform
      async_copy16(Ag + (size_t)(rbase + srow) * N_RED + kbase + scol8,
                   &As[rbase * BK]);
      async_copy16(Bg + (size_t)(rbase + srow) * N_RED + kbase + scol8,
                   &Bs[rbase * BK]);
    }
    __syncthreads();  // compiler emits vmcnt(0) drain before s_barrier

    // ---- fragments + MFMA ----
    bf16x8 a[4], b[4];
#pragma unroll
    for (int m = 0; m < 4; ++m)
      a[m] = *(const bf16x8*)&As[(wr * 64 + m * 16 + fr) * BK + fq * 8];
#pragma unroll
    for (int n = 0; n < 4; ++n)
      b[n] = *(const bf16x8*)&Bs[(wc * 64 + n * 16 + fr) * BK + fq * 8];
#pragma unroll
    for (int m = 0; m < 4; ++m)
#pragma unroll
      for (int n = 0; n < 4; ++n)
        acc[m][n] =
            __builtin_amdgcn_mfma_f32_16x16x32_bf16(a[m], b[n], acc[m][n], 0, 0, 0);
    __syncthreads();
  }

  // ---- epilogue: C/D layout col=lane&15, row=(lane>>4)*4+reg (m89/m91) ----
  float bv[4];
#pragma unroll
  for (int n = 0; n < 4; ++n)
    bv[n] = bias[colTile * BN + wc * 64 + n * 16 + fr];
#pragma unroll
  for (int m = 0; m < 4; ++m) {
    int grow0 = rowTile * BM + wr * 64 + m * 16 + fq * 4;
#pragma unroll
    for (int j = 0; j < 4; ++j) {
      float* crow = C + (size_t)(grow0 + j) * K_OUT;
#pragma unroll
      for (int n = 0; n < 4; ++n)
        crow[colTile * BN + wc * 64 + n * 16 + fr] = acc[m][n][j] + bv[n];
    }
  }
}

// ---------- launch ----------
extern "C" void kernel_launch(void* const* d_in, const int* in_sizes, int n_in,
                              void* d_out, int out_size, void* d_ws, size_t ws_size,
                              hipStream_t stream) {
  const float* x      = (const float*)d_in[0];
  const int*   Wq     = (const int*)d_in[1];
  const float* scales = (const float*)d_in[2];
  const float* zeros  = (const float*)d_in[3];
  const float* mu1    = (const float*)d_in[4];
  const float* mu2    = (const float*)d_in[5];
  const float* bias   = (const float*)d_in[6];
  float* out = (float*)d_out;

  unsigned short* xb = (unsigned short*)d_ws;                       // 64 MiB
  unsigned short* Wb = (unsigned short*)((char*)d_ws +
                         (size_t)M_ROWS * N_RED * sizeof(unsigned short)); // +32 MiB

  // x fp32 -> bf16
  cvt_x_kernel<<<(size_t)M_ROWS * N_RED / 8 / 256, 256, 0, stream>>>(x, xb);
  // W dequant -> bf16
  dequant_w_kernel<<<(size_t)K_OUT * N_RED / 8 / 256, 256, 0, stream>>>(
      Wq, scales, zeros, mu1, mu2, Wb);
  // GEMM + bias
  gemm_bt_kernel<<<(M_ROWS / BM) * (K_OUT / BN), 256, 0, stream>>>(xb, Wb, bias, out);
}

// Round 2
// 519.994 us; speedup vs baseline: 1.1764x; 1.1764x over previous
//
#include <hip/hip_runtime.h>
#include <hip/hip_bf16.h>
#include <stdint.h>

// Problem dims (fixed by reference)
#define M_ROWS 8192   // B*S
#define K_OUT  4096   // K (output features)
#define N_RED  4096   // N (reduction dim)
#define NGRP   32

// GEMM tile (256^2 8-phase template)
#define BM 256
#define BN 256
#define BK 64
#define NKT (N_RED / BK)   // 64 K-tiles

typedef __attribute__((ext_vector_type(8))) __bf16 bf16x8;
typedef __attribute__((ext_vector_type(4))) float   f32x4;

// ---------- helpers ----------

__device__ __forceinline__ unsigned short f32_to_bf16_rn(float f) {
  uint32_t u = __float_as_uint(f);
  uint32_t r = (u + 0x7FFFu + ((u >> 16) & 1u)) >> 16;  // RNE
  return (unsigned short)r;
}

// async global -> LDS, 16 B/lane. LDS dest = wave-uniform base + lane*16;
// global src is per-lane (so swizzle goes on the SOURCE address).
__device__ __forceinline__ void async_copy16(const void* gsrc, void* lds_base) {
  __builtin_amdgcn_global_load_lds(
      (const __attribute__((address_space(1))) uint32_t*)gsrc,
      (__attribute__((address_space(3))) uint32_t*)lds_base,
      16 /*literal*/, 0, 0);
}

// ---------- kernel 1: fused prep (x->bf16, W dequant->bf16) ----------
constexpr size_t XCHUNKS = (size_t)M_ROWS * N_RED / 8;  // 4,194,304
constexpr size_t WCHUNKS = (size_t)K_OUT * N_RED / 8;   // 2,097,152

__global__ __launch_bounds__(256) void prep_kernel(
    const float* __restrict__ x, const int* __restrict__ Wq,
    const float* __restrict__ scales, const float* __restrict__ zeros,
    const float* __restrict__ mu1, const float* __restrict__ mu2,
    unsigned short* __restrict__ xb, unsigned short* __restrict__ Wb) {
  const size_t stride = (size_t)gridDim.x * 256;
  for (size_t c = (size_t)blockIdx.x * 256 + threadIdx.x;
       c < XCHUNKS + WCHUNKS; c += stride) {
    if (c < XCHUNKS) {
      const float4* xp = (const float4*)(x + c * 8);
      float4 v0 = xp[0];
      float4 v1 = xp[1];
      union { unsigned short h[8]; uint4 v; } p;
      p.h[0] = f32_to_bf16_rn(v0.x); p.h[1] = f32_to_bf16_rn(v0.y);
      p.h[2] = f32_to_bf16_rn(v0.z); p.h[3] = f32_to_bf16_rn(v0.w);
      p.h[4] = f32_to_bf16_rn(v1.x); p.h[5] = f32_to_bf16_rn(v1.y);
      p.h[6] = f32_to_bf16_rn(v1.z); p.h[7] = f32_to_bf16_rn(v1.w);
      *(uint4*)(xb + c * 8) = p.v;
    } else {
      size_t idx = c - XCHUNKS;
      int k = (int)(idx >> 9);          // 512 chunks per K-row
      int n = (int)(idx & 511) << 3;
      int g = n >> 7;
      float s  = scales[k * NGRP + g];
      float z  = zeros[k * NGRP + g];
      float sm = s * mu2[k];
      const int4* qp = (const int4*)(Wq + (size_t)k * N_RED + n);
      int4 q0 = qp[0];
      int4 q1 = qp[1];
      const float4* mp = (const float4*)(mu1 + n);
      float4 m0 = mp[0];
      float4 m1 = mp[1];
      union { unsigned short h[8]; uint4 v; } p;
      p.h[0] = f32_to_bf16_rn(((float)q0.x - z) * sm * m0.x);
      p.h[1] = f32_to_bf16_rn(((float)q0.y - z) * sm * m0.y);
      p.h[2] = f32_to_bf16_rn(((float)q0.z - z) * sm * m0.z);
      p.h[3] = f32_to_bf16_rn(((float)q0.w - z) * sm * m0.w);
      p.h[4] = f32_to_bf16_rn(((float)q1.x - z) * sm * m1.x);
      p.h[5] = f32_to_bf16_rn(((float)q1.y - z) * sm * m1.y);
      p.h[6] = f32_to_bf16_rn(((float)q1.z - z) * sm * m1.z);
      p.h[7] = f32_to_bf16_rn(((float)q1.w - z) * sm * m1.w);
      *(uint4*)(Wb + (size_t)k * N_RED + n) = p.v;
    }
  }
}

// ---------- kernel 2: 256^2 8-phase bf16 GEMM, C = A * B^T + bias ----------
// A: [8192][4096] bf16, B: [4096][4096] bf16 (both K-contiguous), C fp32.
// 512 threads = 8 waves (2M x 4N); per-wave 128x64 output = 8x4 frags of
// 16x16x32. LDS: 2 buffers x 4 halves; half h: h&1 = A/B, h>>1 = k-slice
// (32 elems). Half = [256 rows][32 elems] with XOR swizzle on bits 4,5 by
// row bits 2,3 (involution; applied to stage SOURCE and ds_read, LDS dest
// stays linear per global_load_lds rule).
__global__ __launch_bounds__(512, 2) void gemm8_kernel(
    const unsigned short* __restrict__ A, const unsigned short* __restrict__ B,
    const float* __restrict__ bias, float* __restrict__ C) {
  __shared__ __align__(16) unsigned short lds[2][4][8192];  // 128 KiB

  // XCD-bijective swizzle: 512 wgs = 8 XCDs x 64 (4 tileM rows x 16 cols)
  const int bid = blockIdx.x;
  const int wg = (bid & 7) * 64 + (bid >> 3);
  const int tileM = wg >> 4;   // 0..31
  const int tileN = wg & 15;   // 0..15

  const int tid  = threadIdx.x;
  const int wave = tid >> 6;
  const int lane = tid & 63;
  const int wm = wave >> 2;    // 0..1
  const int wn = wave & 3;     // 0..3
  const int fr = lane & 15;
  const int fq = lane >> 4;

  // swizzled per-lane ds_read offset within a half (row = ...*16 + fr):
  const int laneoff =
      (fr * 64 + fq * 16) ^ ((fr & 8) << 2) ^ ((fr & 4) << 2);

  // staging source addresses (inverse-swizzled global)
  const unsigned short* srcA[2];
  const unsigned short* srcB[2];
#pragma unroll
  for (int l = 0; l < 2; ++l) {
    int a = (l * 512 + tid) * 16;  // linear dest byte within half
    int q = a ^ (((a >> 9) & 1) << 5) ^ (((a >> 8) & 1) << 4);
    int row = q >> 6;
    int ce  = (q & 63) >> 1;
    srcA[l] = A + (size_t)(tileM * BM + row) * N_RED + ce;
    srcB[l] = B + (size_t)(tileN * BN + row) * N_RED + ce;
  }
  const int dst0 = wave * 512;          // elems (lane*16B added by HW)
  const int dst1 = 4096 + wave * 512;

  f32x4 acc[8][4] = {};
  bf16x8 af[8], bfr[2];

#define STAGE(nb, h)                                                         \
  do {                                                                       \
    async_copy16(((h) & 1 ? srcB : srcA)[0] + ((h) >> 1) * 32,               \
                 &lds[nb][h][dst0]);                                         \
    async_copy16(((h) & 1 ? srcB : srcA)[1] + ((h) >> 1) * 32,               \
                 &lds[nb][h][dst1]);                                         \
  } while (0)

#define READ_A(cb, ks)                                                       \
  do {                                                                       \
    const char* ab =                                                         \
        (const char*)&lds[cb][(ks) * 2][0] + wm * 8192 + laneoff;            \
    _Pragma("unroll") for (int m = 0; m < 8; ++m)                            \
        af[m] = *(const bf16x8*)(ab + m * 1024);                             \
  } while (0)

#define READ_B(cb, ks, nh)                                                   \
  do {                                                                       \
    const char* bb_ = (const char*)&lds[cb][(ks) * 2 + 1][0] + wn * 4096 +   \
                      laneoff + (nh) * 2048;                                 \
    bfr[0] = *(const bf16x8*)(bb_);                                          \
    bfr[1] = *(const bf16x8*)(bb_ + 1024);                                   \
  } while (0)

#define MFMA_BLK(nh)                                                         \
  do {                                                                       \
    __builtin_amdgcn_s_setprio(1);                                           \
    _Pragma("unroll") for (int m = 0; m < 8; ++m) {                          \
      acc[m][(nh) * 2] = __builtin_amdgcn_mfma_f32_16x16x32_bf16(            \
          af[m], bfr[0], acc[m][(nh) * 2], 0, 0, 0);                         \
      acc[m][(nh) * 2 + 1] = __builtin_amdgcn_mfma_f32_16x16x32_bf16(        \
          af[m], bfr[1], acc[m][(nh) * 2 + 1], 0, 0, 0);                     \
    }                                                                        \
    __builtin_amdgcn_s_setprio(0);                                           \
  } while (0)

  // prologue: stage tile 0 into buf 0 (8 loads outstanding)
#pragma unroll
  for (int h = 0; h < 4; ++h) STAGE(0, h);
  srcA[0] += BK; srcA[1] += BK; srcB[0] += BK; srcB[1] += BK;

  // main loop: compute tile t from buf[t&1], stage tile t+1 into buf[~t&1].
  // vmcnt(4) at ph0/ph2 drains exactly the two halves about to be read.
  for (int t = 0; t < NKT - 1; ++t) {
    const int cb = t & 1, nb = cb ^ 1;
    // ph0: ks0, n-half 0
    asm volatile("s_waitcnt vmcnt(4)" ::: "memory");
    __builtin_amdgcn_s_barrier();
    __builtin_amdgcn_sched_barrier(0);
    READ_A(cb, 0);
    READ_B(cb, 0, 0);
    STAGE(nb, 0);
    MFMA_BLK(0);
    // ph1: ks0, n-half 1
    __builtin_amdgcn_s_barrier();
    __builtin_amdgcn_sched_barrier(0);
    READ_B(cb, 0, 1);
    STAGE(nb, 1);
    MFMA_BLK(1);
    // ph2: ks1, n-half 0
    asm volatile("s_waitcnt vmcnt(4)" ::: "memory");
    __builtin_amdgcn_s_barrier();
    __builtin_amdgcn_sched_barrier(0);
    READ_A(cb, 1);
    READ_B(cb, 1, 0);
    STAGE(nb, 2);
    MFMA_BLK(0);
    // ph3: ks1, n-half 1
    __builtin_amdgcn_s_barrier();
    __builtin_amdgcn_sched_barrier(0);
    READ_B(cb, 1, 1);
    STAGE(nb, 3);
    MFMA_BLK(1);
    srcA[0] += BK; srcA[1] += BK; srcB[0] += BK; srcB[1] += BK;
  }
  // final tile (no staging; drain 4 -> 0)
  {
    const int cb = (NKT - 1) & 1;
    asm volatile("s_waitcnt vmcnt(4)" ::: "memory");
    __builtin_amdgcn_s_barrier();
    __builtin_amdgcn_sched_barrier(0);
    READ_A(cb, 0); READ_B(cb, 0, 0); MFMA_BLK(0);
    __builtin_amdgcn_s_barrier();
    __builtin_amdgcn_sched_barrier(0);
    READ_B(cb, 0, 1); MFMA_BLK(1);
    asm volatile("s_waitcnt vmcnt(0)" ::: "memory");
    __builtin_amdgcn_s_barrier();
    __builtin_amdgcn_sched_barrier(0);
    READ_A(cb, 1); READ_B(cb, 1, 0); MFMA_BLK(0);
    __builtin_amdgcn_s_barrier();
    __builtin_amdgcn_sched_barrier(0);
    READ_B(cb, 1, 1); MFMA_BLK(1);
  }

  // epilogue: C/D layout col=lane&15, row=(lane>>4)*4+reg (m89/m91)
  float bv[4];
#pragma unroll
  for (int n = 0; n < 4; ++n)
    bv[n] = bias[tileN * BN + wn * 64 + n * 16 + fr];
#pragma unroll
  for (int m = 0; m < 8; ++m) {
    int row0 = tileM * BM + wm * 128 + m * 16 + fq * 4;
#pragma unroll
    for (int j = 0; j < 4; ++j) {
      float* crow = C + (size_t)(row0 + j) * K_OUT + tileN * BN + wn * 64 + fr;
#pragma unroll
      for (int n = 0; n < 4; ++n)
        crow[n * 16] = acc[m][n][j] + bv[n];
    }
  }
#undef STAGE
#undef READ_A
#undef READ_B
#undef MFMA_BLK
}

// ---------- launch ----------
extern "C" void kernel_launch(void* const* d_in, const int* in_sizes, int n_in,
                              void* d_out, int out_size, void* d_ws, size_t ws_size,
                              hipStream_t stream) {
  const float* x      = (const float*)d_in[0];
  const int*   Wq     = (const int*)d_in[1];
  const float* scales = (const float*)d_in[2];
  const float* zeros  = (const float*)d_in[3];
  const float* mu1    = (const float*)d_in[4];
  const float* mu2    = (const float*)d_in[5];
  const float* bias   = (const float*)d_in[6];
  float* out = (float*)d_out;

  unsigned short* xb = (unsigned short*)d_ws;                                 // 64 MiB
  unsigned short* Wb = (unsigned short*)((char*)d_ws +
                         (size_t)M_ROWS * N_RED * sizeof(unsigned short));    // +32 MiB

  prep_kernel<<<2048, 256, 0, stream>>>(x, Wq, scales, zeros, mu1, mu2, xb, Wb);
  gemm8_kernel<<<(M_ROWS / BM) * (K_OUT / BN), 512, 0, stream>>>(xb, Wb, bias, out);
}